// Round 1
// 254.842 us; speedup vs baseline: 1.0987x; 1.0987x over previous
//
#include <hip/hip_runtime.h>
#include <hip/hip_bf16.h>
#include <stdint.h>

#define BB 16
#define NN 32
#define TT 256
#define HH 256
#define DD 512
#define EPSF 1e-5f

#define TROWS 32      // fused T-tile rows per block (was 16) -> 2x B-operand reuse
#define ASTRIDE 264   // bf16 A row stride: 132 dw = 4 mod 32 -> <=2-way b128 (free)

typedef __attribute__((ext_vector_type(8))) short short8;
typedef __attribute__((ext_vector_type(4))) float floatx4;

__device__ __forceinline__ unsigned short f2bf(float f) {
    union { float f; unsigned u; } v; v.f = f;
    unsigned u = v.u;
    unsigned r = u + 0x7FFFu + ((u >> 16) & 1u);   // RNE
    return (unsigned short)(r >> 16);
}
__device__ __forceinline__ float bf2f(unsigned short h) {
    union { unsigned u; float f; } v; v.u = ((unsigned)h) << 16;
    return v.f;
}

// ---------------------------------------------------------------------------
// Kernel 1: prep (unchanged).
//  blocks 0..1151   : h = relu(x@W+b). 8 rows x 128 cols per block.
//  blocks 1152..1167: pack W3 -> W3p_hi / W3p_lo (bf16 split, B-frag order)
// ---------------------------------------------------------------------------
__global__ __launch_bounds__(256) void prep_kernel(
    const float* __restrict__ x1, const float* __restrict__ x2,
    const float* __restrict__ W1, const float* __restrict__ b1,
    const float* __restrict__ W2, const float* __restrict__ b2,
    const float* __restrict__ W3,
    float* __restrict__ h1, float* __restrict__ h2,
    unsigned short* __restrict__ W3p_hi, unsigned short* __restrict__ W3p_lo)
{
    const int blk = blockIdx.x;
    const int tid = threadIdx.x;

    if (blk >= 1152) {
        // W3p flat idx o = ((ct*8 + kk)*64 + lane)*8 + j
        //   element = W3[kk*32 + (lane>>4)*8 + j][ct*16 + (lane&15)]
        const int p  = (blk - 1152) * 256 + tid;   // 0..4095
        const int o0 = p * 16;
        unsigned short thi[16], tlo[16];
#pragma unroll
        for (int e = 0; e < 16; ++e) {
            const int o    = o0 + e;
            const int j    = o & 7;
            const int lane = (o >> 3) & 63;
            const int kk   = (o >> 9) & 7;
            const int ct   = o >> 12;
            const int krow = kk * 32 + (lane >> 4) * 8 + j;
            const int col  = ct * 16 + (lane & 15);
            const float w  = W3[krow * HH + col];
            const unsigned short hi = f2bf(w);
            thi[e] = hi;
            tlo[e] = f2bf(w - bf2f(hi));
        }
        unsigned wh[8], wl[8];
#pragma unroll
        for (int e = 0; e < 8; ++e) {
            wh[e] = (unsigned)thi[2 * e] | ((unsigned)thi[2 * e + 1] << 16);
            wl[e] = (unsigned)tlo[2 * e] | ((unsigned)tlo[2 * e + 1] << 16);
        }
        uint4* dh = reinterpret_cast<uint4*>(W3p_hi + o0);
        dh[0] = make_uint4(wh[0], wh[1], wh[2], wh[3]);
        dh[1] = make_uint4(wh[4], wh[5], wh[6], wh[7]);
        uint4* dl = reinterpret_cast<uint4*>(W3p_lo + o0);
        dl[0] = make_uint4(wl[0], wl[1], wl[2], wl[3]);
        dl[1] = make_uint4(wl[4], wl[5], wl[6], wl[7]);
        return;
    }

    __shared__ float xs[8][DD];   // 16 KB

    const int rowgrp  = blk >> 1;
    const int colbase = (blk & 1) * 128;

    const float* x; const float* W; const float* bias; float* h; int row0;
    if (rowgrp < 64) { x = x1; W = W1; bias = b1; h = h1; row0 = rowgrp * 8; }
    else             { x = x2; W = W2; bias = b2; h = h2; row0 = (rowgrp - 64) * 8; }

    {
        const float4* xg = reinterpret_cast<const float4*>(x + (size_t)row0 * DD);
        float4* xl = reinterpret_cast<float4*>(&xs[0][0]);
#pragma unroll
        for (int i = 0; i < 4; ++i) xl[tid + 256 * i] = xg[tid + 256 * i];
    }
    __syncthreads();

    const int jj  = tid & 127;
    const int rh  = tid >> 7;          // wave-uniform
    const int col = colbase + jj;

    float acc[4] = {0.0f, 0.0f, 0.0f, 0.0f};
    const float* Wp = W + col;

    for (int k = 0; k < DD; k += 8) {
        float w[8];
#pragma unroll
        for (int q = 0; q < 8; ++q) w[q] = Wp[(size_t)(k + q) * HH];
#pragma unroll
        for (int r = 0; r < 4; ++r) {
            const float4 xa = *reinterpret_cast<const float4*>(&xs[rh * 4 + r][k]);
            const float4 xb = *reinterpret_cast<const float4*>(&xs[rh * 4 + r][k + 4]);
            float s = acc[r];
            s = fmaf(xa.x, w[0], s); s = fmaf(xa.y, w[1], s);
            s = fmaf(xa.z, w[2], s); s = fmaf(xa.w, w[3], s);
            s = fmaf(xb.x, w[4], s); s = fmaf(xb.y, w[5], s);
            s = fmaf(xb.z, w[6], s); s = fmaf(xb.w, w[7], s);
            acc[r] = s;
        }
    }

    const float bb = bias[col];
#pragma unroll
    for (int r = 0; r < 4; ++r) {
        const float v = acc[r] + bb;
        h[(size_t)(row0 + rh * 4 + r) * HH + col] = v > 0.0f ? v : 0.0f;
    }
}

// ---------------------------------------------------------------------------
// Kernel 2: fused MFMA main — 32-row tiles, register-resident Y, no Ysm.
// One block per (b, n, 32-row T-tile) -> grid 4096. 256 threads = 4 waves.
//   Phase A: A = LN0(h1[b,n,:] * h2[b,t,:]) -> split bf16 Ah/Al (LDS)
//   GEMM:    wave w computes rows 0..31 x cols [w*64, w*64+64) as
//            2 row-tiles x 4 col-tiles; each B frag feeds 6 MFMAs (2x reuse)
//   LN1:     per-row (sum,sumsq) partials from acc regs (in-lane ct-sum +
//            4-step m-shuffle), 2 KB cross-wave exchange, apply + relu +
//            store directly from registers. No Y materialization.
// LDS: 16896*2 + 1024 + 256 = 35,072 B -> 4 blocks/CU.
// ---------------------------------------------------------------------------
__global__ __launch_bounds__(256) void fused_mfma_kernel(
    const float* __restrict__ h1, const float* __restrict__ h2,
    const unsigned short* __restrict__ W3p_hi,
    const unsigned short* __restrict__ W3p_lo,
    const float* __restrict__ b3,
    const float* __restrict__ g0, const float* __restrict__ be0,
    const float* __restrict__ g1, const float* __restrict__ be1,
    float* __restrict__ out)
{
    __shared__ __align__(16) unsigned short Ah_s[TROWS * ASTRIDE];  // 16,896 B
    __shared__ __align__(16) unsigned short Al_s[TROWS * ASTRIDE];  // 16,896 B
    __shared__ float2 Spart[TROWS][4];                              // 1 KB
    __shared__ float2 LNP[TROWS];                                   // 256 B

    const int tid  = threadIdx.x;
    const int wave = tid >> 6;
    const int lane = tid & 63;
    const int blk  = blockIdx.x;
    const int tile = blk & 7;           // 8 tiles of 32 rows
    const int n    = (blk >> 3) & 31;
    const int b    = blk >> 8;

    // ---- Phase A: Hadamard + LN0 -> split bf16 A-tiles (8 rows per wave) --
    {
        const float* h1row = h1 + ((size_t)b * NN + n) * HH;
        const float4 h1v  = *reinterpret_cast<const float4*>(h1row + 4 * lane);
        const float4 g0v  = *reinterpret_cast<const float4*>(g0  + 4 * lane);
        const float4 be0v = *reinterpret_cast<const float4*>(be0 + 4 * lane);
        const float* h2b  = h2 + ((size_t)b * TT + tile * TROWS) * HH;

#pragma unroll 2
        for (int i = 0; i < 8; ++i) {
            const int r = wave * 8 + i;
            float4 v = *reinterpret_cast<const float4*>(h2b + (size_t)r * HH + 4 * lane);
            v.x *= h1v.x; v.y *= h1v.y; v.z *= h1v.z; v.w *= h1v.w;
            float s = v.x + v.y + v.z + v.w;
            float q = v.x * v.x + v.y * v.y + v.z * v.z + v.w * v.w;
#pragma unroll
            for (int off = 32; off >= 1; off >>= 1) {
                s += __shfl_xor(s, off, 64);
                q += __shfl_xor(q, off, 64);
            }
            const float mu  = s * (1.0f / HH);
            const float var = q * (1.0f / HH) - mu * mu;
            const float rs  = rsqrtf(var + EPSF);
            float af[4];
            af[0] = (v.x - mu) * rs * g0v.x + be0v.x;
            af[1] = (v.y - mu) * rs * g0v.y + be0v.y;
            af[2] = (v.z - mu) * rs * g0v.z + be0v.z;
            af[3] = (v.w - mu) * rs * g0v.w + be0v.w;
            ushort4 ahi, alo;
            ahi.x = f2bf(af[0]); alo.x = f2bf(af[0] - bf2f(ahi.x));
            ahi.y = f2bf(af[1]); alo.y = f2bf(af[1] - bf2f(ahi.y));
            ahi.z = f2bf(af[2]); alo.z = f2bf(af[2] - bf2f(ahi.z));
            ahi.w = f2bf(af[3]); alo.w = f2bf(af[3] - bf2f(ahi.w));
            *reinterpret_cast<ushort4*>(&Ah_s[r * ASTRIDE + 4 * lane]) = ahi;
            *reinterpret_cast<ushort4*>(&Al_s[r * ASTRIDE + 4 * lane]) = alo;
        }
    }
    __syncthreads();

    // ---- MFMA GEMM: wave -> rows 0..31 (2 rt), cols [wave*64, +64) (4 ct) -
    const int m  = lane & 15;
    const int qd = lane >> 4;

    floatx4 acc[2][4];
#pragma unroll
    for (int ct = 0; ct < 4; ++ct) {
        const float bv = b3[wave * 64 + ct * 16 + m];
#pragma unroll
        for (int rt = 0; rt < 2; ++rt) {
            acc[rt][ct][0] = bv; acc[rt][ct][1] = bv;
            acc[rt][ct][2] = bv; acc[rt][ct][3] = bv;
        }
    }

#pragma unroll 2
    for (int kk = 0; kk < 8; ++kk) {
        short8 bh[4], bl[4];
#pragma unroll
        for (int ct = 0; ct < 4; ++ct) {
            const size_t off = ((size_t)((wave * 4 + ct) * 8 + kk) * 64 + lane) * 8;
            bh[ct] = *reinterpret_cast<const short8*>(W3p_hi + off);
            bl[ct] = *reinterpret_cast<const short8*>(W3p_lo + off);
        }
#pragma unroll
        for (int rt = 0; rt < 2; ++rt) {
            const int aoff = (rt * 16 + m) * ASTRIDE + kk * 32 + qd * 8;
            const short8 ah = *reinterpret_cast<const short8*>(&Ah_s[aoff]);
            const short8 al = *reinterpret_cast<const short8*>(&Al_s[aoff]);
#pragma unroll
            for (int ct = 0; ct < 4; ++ct) {
                floatx4 c = acc[rt][ct];
                c = __builtin_amdgcn_mfma_f32_16x16x32_bf16(ah, bh[ct], c, 0, 0, 0);
                c = __builtin_amdgcn_mfma_f32_16x16x32_bf16(al, bh[ct], c, 0, 0, 0);
                c = __builtin_amdgcn_mfma_f32_16x16x32_bf16(ah, bl[ct], c, 0, 0, 0);
                acc[rt][ct] = c;
            }
        }
    }

    // ---- LN1 from registers: per-row partials -> 2KB exchange -------------
    // acc element (rt,ct,reg) = Y[row = rt*16 + qd*4 + reg][col = wave*64 + ct*16 + m]
    {
        float ssum[8], qsum[8];       // [rt*4 + reg]
#pragma unroll
        for (int rt = 0; rt < 2; ++rt)
#pragma unroll
            for (int reg = 0; reg < 4; ++reg) {
                float s = 0.0f, q = 0.0f;
#pragma unroll
                for (int ct = 0; ct < 4; ++ct) {
                    const float y = acc[rt][ct][reg];
                    s += y; q = fmaf(y, y, q);
                }
                ssum[rt * 4 + reg] = s; qsum[rt * 4 + reg] = q;
            }
#pragma unroll
        for (int off = 1; off < 16; off <<= 1) {
#pragma unroll
            for (int e = 0; e < 8; ++e) {
                ssum[e] += __shfl_xor(ssum[e], off, 64);
                qsum[e] += __shfl_xor(qsum[e], off, 64);
            }
        }
        if (m == 0) {
#pragma unroll
            for (int rt = 0; rt < 2; ++rt)
#pragma unroll
                for (int reg = 0; reg < 4; ++reg) {
                    const int row = rt * 16 + qd * 4 + reg;
                    Spart[row][wave] = make_float2(ssum[rt * 4 + reg], qsum[rt * 4 + reg]);
                }
        }
    }
    __syncthreads();

    if (tid < TROWS) {
        float s = 0.0f, q = 0.0f;
#pragma unroll
        for (int w = 0; w < 4; ++w) {
            const float2 p = Spart[tid][w];
            s += p.x; q += p.y;
        }
        const float mu  = s * (1.0f / HH);
        const float var = q * (1.0f / HH) - mu * mu;
        LNP[tid] = make_float2(mu, rsqrtf(var + EPSF));
    }
    __syncthreads();

    // ---- apply LN1 + relu + store straight from acc -----------------------
    {
        const int colb = wave * 64;
        float g1c[4], be1c[4];
#pragma unroll
        for (int ct = 0; ct < 4; ++ct) {
            g1c[ct]  = g1[colb + ct * 16 + m];
            be1c[ct] = be1[colb + ct * 16 + m];
        }
        float* outb = out + (((size_t)b * NN + n) * TT + tile * TROWS) * HH;

#pragma unroll
        for (int rt = 0; rt < 2; ++rt)
#pragma unroll
            for (int reg = 0; reg < 4; ++reg) {
                const int row = rt * 16 + qd * 4 + reg;
                const float2 p = LNP[row];   // (mu, rs)
#pragma unroll
                for (int ct = 0; ct < 4; ++ct) {
                    const float y = acc[rt][ct][reg];
                    const float o = fmaxf((y - p.x) * p.y * g1c[ct] + be1c[ct], 0.0f);
                    outb[(size_t)row * HH + colb + ct * 16 + m] = o;
                }
            }
    }
}

// ---------------------------------------------------------------------------
extern "C" void kernel_launch(void* const* d_in, const int* in_sizes, int n_in,
                              void* d_out, int out_size, void* d_ws, size_t ws_size,
                              hipStream_t stream) {
    const float* x1  = (const float*)d_in[0];
    const float* x2  = (const float*)d_in[1];
    const float* W1  = (const float*)d_in[2];
    const float* b1  = (const float*)d_in[3];
    const float* W2  = (const float*)d_in[4];
    const float* b2  = (const float*)d_in[5];
    const float* W3  = (const float*)d_in[6];
    const float* b3  = (const float*)d_in[7];
    const float* g0  = (const float*)d_in[8];
    const float* be0 = (const float*)d_in[9];
    const float* g1  = (const float*)d_in[10];
    const float* be1 = (const float*)d_in[11];
    float* out = (float*)d_out;

    // Workspace: h1 (0.5 MB) | h2 (4 MB) | W3p_hi (128 KB) | W3p_lo (128 KB)
    float* h1 = (float*)d_ws;
    float* h2 = h1 + (size_t)BB * NN * HH;
    unsigned short* W3p_hi = (unsigned short*)(h2 + (size_t)BB * TT * HH);
    unsigned short* W3p_lo = W3p_hi + (size_t)HH * HH;

    hipLaunchKernelGGL(prep_kernel, dim3(1168), dim3(256), 0, stream,
                       x1, x2, W1, b1, W2, b2, W3, h1, h2, W3p_hi, W3p_lo);

    hipLaunchKernelGGL(fused_mfma_kernel, dim3(4096), dim3(256), 0, stream,
                       h1, h2, W3p_hi, W3p_lo, b3, g0, be0, g1, be1, out);
}